// Round 10
// baseline (186.298 us; speedup 1.0000x reference)
//
#include <hip/hip_runtime.h>
#include <hip/hip_bf16.h>
#include <stdint.h>

#define NBATCH 4
#define NV 2048
#define NC 8192
#define DD 64

typedef __attribute__((ext_vector_type(8))) short s16x8;
typedef __attribute__((ext_vector_type(4))) float fx4;
typedef __attribute__((ext_vector_type(8))) unsigned short u16x8;
typedef __attribute__((ext_vector_type(4))) int i32x4;
typedef __attribute__((ext_vector_type(2))) unsigned int u32x2;

static __device__ __forceinline__ void gload_lds16(const void* g, void* l) {
    __builtin_amdgcn_global_load_lds(
        (const __attribute__((address_space(1))) unsigned int*)g,
        (__attribute__((address_space(3))) unsigned int*)l, 16, 0, 0);
}

// ---------------------------------------------------------------------------
// K0: s=(pos+neg)/2, d=(pos-neg)/2 of variables @ c_block[pn]^T, quantized to
// int16 (scale 2^12), split hi/lo i8, i8 MFMA B-frag layout.
// ---------------------------------------------------------------------------
__global__ __launch_bounds__(256) void k_prep_pv(
    const float* __restrict__ vars, const float* __restrict__ cblk,
    char* __restrict__ qsh, char* __restrict__ qsl,
    char* __restrict__ qdh, char* __restrict__ qdl)
{
    __shared__ float sv[32][64];
    __shared__ float scb[2][64][65];
    int blk = blockIdx.x;
    int b = blk >> 6, ch = blk & 63;
    int t = threadIdx.x;
    const float* vsrc = vars + ((size_t)b * NV + (size_t)ch * 32) * DD;
    for (int i = t; i < 32 * 64; i += 256) sv[i >> 6][i & 63] = vsrc[i];
    for (int i = t; i < 2 * 64 * 64; i += 256) {
        int pn = i >> 12, dout = (i >> 6) & 63, k = i & 63;
        scb[pn][k][dout] = cblk[i];
    }
    __syncthreads();
    int ks = t >> 6, dout = t & 63;
    unsigned int wsh[2] = {0, 0}, wsl[2] = {0, 0}, wdh[2] = {0, 0}, wdl[2] = {0, 0};
    #pragma unroll
    for (int c8 = 0; c8 < 8; ++c8) {
        int vloc = ks * 8 + c8;
        float ap = 0.f, an = 0.f;
        for (int k = 0; k < 64; ++k) {
            float vv = sv[vloc][k];
            ap += vv * scb[0][k][dout];
            an += vv * scb[1][k][dout];
        }
        float s = (ap + an) * 0.5f, dv = (ap - an) * 0.5f;
        int qs_ = (int)rintf(s * 4096.f);
        int qd_ = (int)rintf(dv * 4096.f);
        qs_ = min(max(qs_, -32511), 32511);
        qd_ = min(max(qd_, -32511), 32511);
        int sh = (qs_ + 128) >> 8, sl = qs_ - (sh << 8);
        int dh = (qd_ + 128) >> 8, dl = qd_ - (dh << 8);
        int w = c8 >> 2, sft = (c8 & 3) * 8;
        wsh[w] |= (unsigned int)(sh & 0xFF) << sft;
        wsl[w] |= (unsigned int)(sl & 0xFF) << sft;
        wdh[w] |= (unsigned int)(dh & 0xFF) << sft;
        wdl[w] |= (unsigned int)(dl & 0xFF) << sft;
    }
    int kc = ch >> 1;
    int lg = ((ch & 1) << 1) | (ks >> 1);
    size_t off = (((size_t)(b * 32 + kc) * 64 + dout) * 4 + lg) * 16 + (ks & 1) * 8;
    *(u32x2*)(qsh + off) = (u32x2){wsh[0], wsh[1]};
    *(u32x2*)(qsl + off) = (u32x2){wsl[0], wsl[1]};
    *(u32x2*)(qdh + off) = (u32x2){wdh[0], wdh[1]};
    *(u32x2*)(qdl + off) = (u32x2){wdl[0], wdl[1]};
}

// ---------------------------------------------------------------------------
// K-compress: pure streaming. cmat (256 MB f32) -> (a) asgn sign-bytes in
// exact i8 MFMA A-frag layout [b][frag=0..127][crow=0..8191][16B] (64 MB),
// (b) comp 2-bit codes [b][v8=0..255][crow] ushort (16 MB).
// Tile: 64 rows x 256 vars per block; LDS transpose; all I/O >=1KB coalesced.
// grid 4096 x 256: blk = b*1024 + rg*8 + tv.
// ---------------------------------------------------------------------------
__global__ __launch_bounds__(256) void k_compress(
    const float* __restrict__ cmat,
    char* __restrict__ asgn, unsigned short* __restrict__ comp)
{
    __shared__ char sb[64][272];
    int blk = blockIdx.x;
    int tv = blk & 7;
    int rg = (blk >> 3) & 127;
    int b = blk >> 10;
    int t = threadIdx.x;
    int wv = t >> 6, l = t & 63;
    int crow0 = rg * 64;
    const float* src = cmat + (size_t)b * NC * NV + (size_t)crow0 * NV + tv * 256;
    // in: each wave 16 rows, 1 KB per row per instr
    #pragma unroll 4
    for (int rr = 0; rr < 16; ++rr) {
        int r = wv * 16 + rr;
        fx4 x = *(const fx4*)(src + (size_t)r * NV + l * 4);
        unsigned int pk = ((unsigned int)((int)x[0] & 0xFF))
                        | (((unsigned int)((int)x[1] & 0xFF)) << 8)
                        | (((unsigned int)((int)x[2] & 0xFF)) << 16)
                        | (((unsigned int)((int)x[3] & 0xFF)) << 24);
        *(unsigned int*)&sb[r][l * 4] = pk;
    }
    __syncthreads();
    // asgn out: wave wv handles frags f = wv*4..+4; lane l -> row l. 1 KB/instr.
    size_t abase = ((size_t)(b * 128 + tv * 16)) * 8192 * 16;
    #pragma unroll
    for (int ff = 0; ff < 4; ++ff) {
        int f = wv * 4 + ff;
        i32x4 v = *(const i32x4*)&sb[l][f * 16];
        *(i32x4*)(asgn + abase + ((size_t)f * 8192 + crow0 + l) * 16) = v;
    }
    // comp out: 2048 ushorts, rows contiguous (128-B segments)
    unsigned short* cbp = comp + ((size_t)b * 256 + tv * 32) * NC + crow0;
    #pragma unroll
    for (int it = 0; it < 8; ++it) {
        int idx = it * 256 + t;
        int v8l = idx >> 6, r = idx & 63;
        const unsigned char* p = (const unsigned char*)&sb[r][v8l * 8];
        unsigned int c0 = 0;
        #pragma unroll
        for (int i = 0; i < 8; ++i) c0 |= ((unsigned int)(p[i] & 3u)) << (2 * i);
        cbp[(size_t)v8l * NC + r] = (unsigned short)c0;
    }
}

// ---------------------------------------------------------------------------
// K1: i8 phase A, A-frags direct from asgn (1 dwordx4/chunk/rt, L3-warm),
// zero conversion VALU, no comp duty. cpart[q][b][c][d] raw-scaled partial.
// 128-row 4-wave blocks, K-quarter q, B-planes gload_lds dbuf. grid 1024x256.
// ---------------------------------------------------------------------------
__global__ __launch_bounds__(256, 4) void k_phaseA(
    const char* __restrict__ asgn,
    const char* __restrict__ qsh, const char* __restrict__ qsl,
    const char* __restrict__ qdh, const char* __restrict__ qdl,
    float* __restrict__ cpart)
{
    __shared__ char lds[2][16384];
    int blk = blockIdx.x;
    int combo = blk & 15;
    int rg = blk >> 4;
    int b = combo >> 2;
    int q = combo & 3;
    int t = threadIdx.x;
    int wv = t >> 6, l = t & 63, lr = l & 15, lg = l >> 4;
    int c0 = rg * 128 + wv * 32;

    i32x4 ahi[2][4], alo[2][4];
    #pragma unroll
    for (int i = 0; i < 2; ++i)
        #pragma unroll
        for (int j = 0; j < 4; ++j) { ahi[i][j] = (i32x4){0,0,0,0}; alo[i][j] = (i32x4){0,0,0,0}; }

    {
        size_t gb = ((size_t)(b * 32 + q * 8)) * 4096 + (size_t)t * 16;
        char* lp = &lds[0][t * 16];
        gload_lds16(qsh + gb, lp);
        gload_lds16(qsl + gb, lp + 4096);
        gload_lds16(qdh + gb, lp + 8192);
        gload_lds16(qdl + gb, lp + 12288);
    }
    __syncthreads();

    int cur = 0;
    #pragma unroll 1
    for (int cc = 0; cc < 8; ++cc) {
        int kc = q * 8 + cc;
        if (cc < 7) {
            size_t gb = ((size_t)(b * 32 + kc + 1)) * 4096 + (size_t)t * 16;
            char* lp = &lds[cur ^ 1][t * 16];
            gload_lds16(qsh + gb, lp);
            gload_lds16(qsl + gb, lp + 4096);
            gload_lds16(qdh + gb, lp + 8192);
            gload_lds16(qdl + gb, lp + 12288);
        }
        // A-frags: one dwordx4 per rt from pre-swizzled asgn
        i32x4 Asgn[2], Aabs[2];
        #pragma unroll
        for (int rt = 0; rt < 2; ++rt) {
            size_t ao = (((size_t)(b * 128 + kc * 4 + lg)) * 8192
                         + (size_t)(c0 + rt * 16 + lr)) * 16;
            i32x4 sg = *(const i32x4*)(asgn + ao);
            Asgn[rt] = sg;
            i32x4 ab;
            #pragma unroll
            for (int w = 0; w < 4; ++w) ab[w] = sg[w] & 0x01010101;
            Aabs[rt] = ab;
        }
        const char* bufp = lds[cur];
        #pragma unroll
        for (int n = 0; n < 4; ++n) {
            int boff = ((n * 16 + lr) * 4 + lg) * 16;
            i32x4 Bsh = *(const i32x4*)(bufp + boff);
            i32x4 Bsl = *(const i32x4*)(bufp + 4096 + boff);
            i32x4 Bdh = *(const i32x4*)(bufp + 8192 + boff);
            i32x4 Bdl = *(const i32x4*)(bufp + 12288 + boff);
            #pragma unroll
            for (int rt = 0; rt < 2; ++rt) {
                ahi[rt][n] = __builtin_amdgcn_mfma_i32_16x16x64_i8(Aabs[rt], Bsh, ahi[rt][n], 0, 0, 0);
                ahi[rt][n] = __builtin_amdgcn_mfma_i32_16x16x64_i8(Asgn[rt], Bdh, ahi[rt][n], 0, 0, 0);
                alo[rt][n] = __builtin_amdgcn_mfma_i32_16x16x64_i8(Aabs[rt], Bsl, alo[rt][n], 0, 0, 0);
                alo[rt][n] = __builtin_amdgcn_mfma_i32_16x16x64_i8(Asgn[rt], Bdl, alo[rt][n], 0, 0, 0);
            }
        }
        __syncthreads();
        cur ^= 1;
    }
    float* dst = cpart + (((size_t)q * NBATCH + b) * NC + c0) * DD;
    #pragma unroll
    for (int rt = 0; rt < 2; ++rt)
        #pragma unroll
        for (int n = 0; n < 4; ++n)
            #pragma unroll
            for (int r = 0; r < 4; ++r) {
                float v = (float)(ahi[rt][n][r] * 256 + alo[rt][n][r]) * (1.0f / 4096.0f);
                dst[(size_t)(rt * 16 + lg * 4 + r) * DD + n * 16 + lr] = v;
            }
}

// ---------------------------------------------------------------------------
// K2: c = relu(sum_q cpart + cb); emit (c@v0^T +/- c@v1^T)/2 quantized int16
// (scale 2^9), split hi/lo i8, i8 B-frag layout.
// ---------------------------------------------------------------------------
__global__ __launch_bounds__(256) void k_projC(
    const float* __restrict__ cpart, const float* __restrict__ cb,
    const float* __restrict__ vblk,
    char* __restrict__ csh, char* __restrict__ csl,
    char* __restrict__ cdh, char* __restrict__ cdl)
{
    __shared__ float src[32][64];
    __shared__ float svb[2][64][65];
    int blk = blockIdx.x;
    int b = blk >> 8, kc32 = blk & 255;
    int t = threadIdx.x;
    const size_t qs = (size_t)NBATCH * NC * DD;
    const float* cs = cpart + ((size_t)b * NC + (size_t)kc32 * 32) * DD;
    for (int i = t; i < 2048; i += 256) {
        int k = i & 63;
        float v = cb[k];
        #pragma unroll
        for (int p = 0; p < 4; ++p) v += cs[i + p * qs];
        src[i >> 6][k] = fmaxf(v, 0.f);
    }
    for (int i = t; i < 8192; i += 256) {
        int pn = i >> 12, dout = (i >> 6) & 63, k = i & 63;
        svb[pn][k][dout] = vblk[i];
    }
    __syncthreads();
    int ks = t >> 6, dout = t & 63;
    float ap[8] = {0.f, 0.f, 0.f, 0.f, 0.f, 0.f, 0.f, 0.f};
    float an[8] = {0.f, 0.f, 0.f, 0.f, 0.f, 0.f, 0.f, 0.f};
    for (int k = 0; k < 64; ++k) {
        float w0 = svb[0][k][dout], w1 = svb[1][k][dout];
        #pragma unroll
        for (int c8 = 0; c8 < 8; ++c8) {
            float rc = src[ks * 8 + c8][k];
            ap[c8] += rc * w0;
            an[c8] += rc * w1;
        }
    }
    unsigned int wsh[2] = {0, 0}, wsl[2] = {0, 0}, wdh[2] = {0, 0}, wdl[2] = {0, 0};
    #pragma unroll
    for (int c8 = 0; c8 < 8; ++c8) {
        float s = (ap[c8] + an[c8]) * 0.5f, dv = (ap[c8] - an[c8]) * 0.5f;
        int q_s = (int)rintf(s * 512.f);
        int q_d = (int)rintf(dv * 512.f);
        q_s = min(max(q_s, -32511), 32511);
        q_d = min(max(q_d, -32511), 32511);
        int sh = (q_s + 128) >> 8, sl = q_s - (sh << 8);
        int dh = (q_d + 128) >> 8, dl = q_d - (dh << 8);
        int w = c8 >> 2, sft = (c8 & 3) * 8;
        wsh[w] |= (unsigned int)(sh & 0xFF) << sft;
        wsl[w] |= (unsigned int)(sl & 0xFF) << sft;
        wdh[w] |= (unsigned int)(dh & 0xFF) << sft;
        wdl[w] |= (unsigned int)(dl & 0xFF) << sft;
    }
    int kc = kc32 >> 1;
    int lgw = ((kc32 & 1) << 1) | (ks >> 1);
    size_t off = (((size_t)(b * 128 + kc) * 64 + dout) * 4 + lgw) * 16 + (ks & 1) * 8;
    *(u32x2*)(csh + off) = (u32x2){wsh[0], wsh[1]};
    *(u32x2*)(csl + off) = (u32x2){wsl[0], wsl[1]};
    *(u32x2*)(cdh + off) = (u32x2){wdh[0], wdh[1]};
    *(u32x2*)(cdl + off) = (u32x2){wdl[0], wdl[1]};
}

// ---------------------------------------------------------------------------
// K3: i8 phase B. npart[q][b][v][d] = (|A|@s + A@d)/512 over K-16th q,
// A decoded from comp codes. 128-row 4-wave blocks, gload_lds dbuf.
// grid 1024 x 256.
// ---------------------------------------------------------------------------
__global__ __launch_bounds__(256, 4) void k_phaseB(
    const unsigned short* __restrict__ comp,
    const char* __restrict__ csh, const char* __restrict__ csl,
    const char* __restrict__ cdh, const char* __restrict__ cdl,
    float* __restrict__ npart)
{
    __shared__ char lds[2][16384];
    int blk = blockIdx.x;
    int combo = blk & 63;
    int rg = blk >> 6;
    int b = combo >> 4;
    int q = combo & 15;
    int t = threadIdx.x;
    int wv = t >> 6, l = t & 63, lr = l & 15, lg = l >> 4;
    int v0 = rg * 128 + wv * 32;
    const unsigned short* compb = comp + (size_t)b * 256 * NC;
    int sh_ = 2 * (lr & 7);
    const unsigned short* cp0 = compb + (size_t)((v0 + lr) >> 3) * NC + q * 512 + lg * 16;
    const unsigned short* cp1 = compb + (size_t)((v0 + 16 + lr) >> 3) * NC + q * 512 + lg * 16;
    const size_t cbase = ((size_t)(b * 128 + q * 8)) * 4096;

    i32x4 ahi[2][4], alo[2][4];
    #pragma unroll
    for (int i = 0; i < 2; ++i)
        #pragma unroll
        for (int j = 0; j < 4; ++j) { ahi[i][j] = (i32x4){0,0,0,0}; alo[i][j] = (i32x4){0,0,0,0}; }

    {
        size_t gb = cbase + (size_t)t * 16;
        char* lp = &lds[0][t * 16];
        gload_lds16(csh + gb, lp);
        gload_lds16(csl + gb, lp + 4096);
        gload_lds16(cdh + gb, lp + 8192);
        gload_lds16(cdl + gb, lp + 12288);
    }
    __syncthreads();

    int cur = 0;
    #pragma unroll 1
    for (int cc = 0; cc < 8; ++cc) {
        u16x8 u00 = *(const u16x8*)(cp0 + cc * 64);
        u16x8 u01 = *(const u16x8*)(cp0 + cc * 64 + 8);
        u16x8 u10 = *(const u16x8*)(cp1 + cc * 64);
        u16x8 u11 = *(const u16x8*)(cp1 + cc * 64 + 8);
        if (cc < 7) {
            size_t gb = cbase + (size_t)(cc + 1) * 4096 + (size_t)t * 16;
            char* lp = &lds[cur ^ 1][t * 16];
            gload_lds16(csh + gb, lp);
            gload_lds16(csl + gb, lp + 4096);
            gload_lds16(cdh + gb, lp + 8192);
            gload_lds16(cdl + gb, lp + 12288);
        }
        i32x4 Asgn[2], Aabs[2];
        #pragma unroll
        for (int rt = 0; rt < 2; ++rt) {
            u16x8 ua = rt ? u10 : u00;
            u16x8 ub = rt ? u11 : u01;
            i32x4 sg;
            #pragma unroll
            for (int g = 0; g < 4; ++g) {
                unsigned int wg = 0;
                #pragma unroll
                for (int jj = 0; jj < 4; ++jj) {
                    int j = g * 4 + jj;
                    unsigned int code = ((unsigned int)(j < 8 ? ua[j & 7] : ub[j & 7]) >> sh_) & 3u;
                    unsigned int byt = (code == 3u) ? 0xFFu : code;
                    wg |= byt << (jj * 8);
                }
                sg[g] = (int)wg;
            }
            Asgn[rt] = sg;
            i32x4 ab;
            #pragma unroll
            for (int g = 0; g < 4; ++g) ab[g] = sg[g] & 0x01010101;
            Aabs[rt] = ab;
        }
        const char* bufp = lds[cur];
        #pragma unroll
        for (int n = 0; n < 4; ++n) {
            int boff = ((n * 16 + lr) * 4 + lg) * 16;
            i32x4 Bsh = *(const i32x4*)(bufp + boff);
            i32x4 Bsl = *(const i32x4*)(bufp + 4096 + boff);
            i32x4 Bdh = *(const i32x4*)(bufp + 8192 + boff);
            i32x4 Bdl = *(const i32x4*)(bufp + 12288 + boff);
            #pragma unroll
            for (int rt = 0; rt < 2; ++rt) {
                ahi[rt][n] = __builtin_amdgcn_mfma_i32_16x16x64_i8(Aabs[rt], Bsh, ahi[rt][n], 0, 0, 0);
                ahi[rt][n] = __builtin_amdgcn_mfma_i32_16x16x64_i8(Asgn[rt], Bdh, ahi[rt][n], 0, 0, 0);
                alo[rt][n] = __builtin_amdgcn_mfma_i32_16x16x64_i8(Aabs[rt], Bsl, alo[rt][n], 0, 0, 0);
                alo[rt][n] = __builtin_amdgcn_mfma_i32_16x16x64_i8(Asgn[rt], Bdl, alo[rt][n], 0, 0, 0);
            }
        }
        __syncthreads();
        cur ^= 1;
    }
    float* dst = npart + (((size_t)q * NBATCH + b) * NV + v0) * DD;
    #pragma unroll
    for (int rt = 0; rt < 2; ++rt)
        #pragma unroll
        for (int n = 0; n < 4; ++n)
            #pragma unroll
            for (int r = 0; r < 4; ++r) {
                float v = (float)(ahi[rt][n][r] * 256 + alo[rt][n][r]) * (1.0f / 512.0f);
                dst[(size_t)(rt * 16 + lg * 4 + r) * DD + n * 16 + lr] = v;
            }
}

// ---------------------------------------------------------------------------
// K4: v_emb=relu(sum_{q<16} npart+vb); av=tanh([g|v_emb]@Wg^T+bg); GRU -> out
// grid 256 x 512, 4 row-iterations per block.
// ---------------------------------------------------------------------------
__global__ __launch_bounds__(512) void k_gru(
    const float* __restrict__ npart, const float* __restrict__ vars,
    const float* __restrict__ gv, const float* __restrict__ vb,
    const float* __restrict__ Wg, const float* __restrict__ bg,
    const float* __restrict__ Wz, const float* __restrict__ Uz, const float* __restrict__ bz,
    const float* __restrict__ Wr, const float* __restrict__ Ur, const float* __restrict__ brr,
    const float* __restrict__ Wh, const float* __restrict__ Uh, const float* __restrict__ bh,
    float* __restrict__ out)
{
    __shared__ float sWg[72][65];
    __shared__ float sWz[64][65], sUz[64][65];
    __shared__ float sWr[64][65], sUr[64][65];
    __shared__ float sWh[64][65], sUh[64][65];
    __shared__ float scat[8][72];
    __shared__ float sprev[8][64];
    __shared__ float sav[8][64];
    __shared__ float srp[8][64];
    int t = threadIdx.x;
    for (int i = t * 4; i < 4608; i += 2048) {
        fx4 g4 = *(const fx4*)(Wg + i);
        int dout = i / 72, j = i - dout * 72;
        #pragma unroll
        for (int jj = 0; jj < 4; ++jj) sWg[j + jj][dout] = g4[jj];
    }
    for (int i = t * 4; i < 4096; i += 2048) {
        int dout = i >> 6, k = i & 63;
        fx4 a;
        a = *(const fx4*)(Wz + i);
        #pragma unroll
        for (int jj = 0; jj < 4; ++jj) sWz[k + jj][dout] = a[jj];
        a = *(const fx4*)(Uz + i);
        #pragma unroll
        for (int jj = 0; jj < 4; ++jj) sUz[k + jj][dout] = a[jj];
        a = *(const fx4*)(Wr + i);
        #pragma unroll
        for (int jj = 0; jj < 4; ++jj) sWr[k + jj][dout] = a[jj];
        a = *(const fx4*)(Ur + i);
        #pragma unroll
        for (int jj = 0; jj < 4; ++jj) sUr[k + jj][dout] = a[jj];
        a = *(const fx4*)(Wh + i);
        #pragma unroll
        for (int jj = 0; jj < 4; ++jj) sWh[k + jj][dout] = a[jj];
        a = *(const fx4*)(Uh + i);
        #pragma unroll
        for (int jj = 0; jj < 4; ++jj) sUh[k + jj][dout] = a[jj];
    }
    int rr = t >> 6, dout = t & 63;
    const size_t qs = (size_t)NBATCH * NV * DD;
    #pragma unroll 1
    for (int it = 0; it < 4; ++it) {
        size_t row = (size_t)blockIdx.x * 32 + it * 8 + rr;
        float prev = vars[row * 64 + dout];
        float ve = vb[dout];
        #pragma unroll
        for (int s = 0; s < 16; ++s) ve += npart[(size_t)s * qs + row * 64 + dout];
        ve = fmaxf(ve, 0.f);
        scat[rr][8 + dout] = ve;
        if (dout < 8) scat[rr][dout] = gv[row * 8 + dout];
        sprev[rr][dout] = prev;
        __syncthreads();
        float a = bg[dout];
        for (int j = 0; j < 72; ++j) a += scat[rr][j] * sWg[j][dout];
        float av = 1.f - 2.f / (__expf(2.f * a) + 1.f);
        sav[rr][dout] = av;
        __syncthreads();
        float zi = bz[dout], ri = brr[dout], hwa = 0.f;
        for (int k = 0; k < 64; ++k) {
            float ak = sav[rr][k], pk = sprev[rr][k];
            zi += ak * sWz[k][dout] + pk * sUz[k][dout];
            ri += ak * sWr[k][dout] + pk * sUr[k][dout];
            hwa += ak * sWh[k][dout];
        }
        float z = 1.f / (1.f + __expf(-zi));
        float rgate = 1.f / (1.f + __expf(-ri));
        srp[rr][dout] = rgate * prev;
        __syncthreads();
        float hin = bh[dout] + hwa;
        for (int k = 0; k < 64; ++k) hin += srp[rr][k] * sUh[k][dout];
        float ht = 1.f - 2.f / (__expf(2.f * hin) + 1.f);
        out[row * 64 + dout] = (1.f - z) * prev + z * ht;
        __syncthreads();
    }
}

// ---------------------------------------------------------------------------
extern "C" void kernel_launch(void* const* d_in, const int* in_sizes, int n_in,
                              void* d_out, int out_size, void* d_ws, size_t ws_size,
                              hipStream_t stream) {
    (void)in_sizes; (void)n_in; (void)out_size; (void)ws_size;
    const float* vars = (const float*)d_in[0];
    const float* gv   = (const float*)d_in[1];
    const float* cmat = (const float*)d_in[2];
    const float* cblk = (const float*)d_in[4];
    const float* vblk = (const float*)d_in[5];
    const float* vb   = (const float*)d_in[6];
    const float* cb   = (const float*)d_in[7];
    const float* Wg   = (const float*)d_in[8];
    const float* bg   = (const float*)d_in[9];
    const float* Wz   = (const float*)d_in[10];
    const float* Uz   = (const float*)d_in[11];
    const float* bz   = (const float*)d_in[12];
    const float* Wr   = (const float*)d_in[13];
    const float* Ur   = (const float*)d_in[14];
    const float* br_  = (const float*)d_in[15];
    const float* Wh   = (const float*)d_in[16];
    const float* Uh   = (const float*)d_in[17];
    const float* bh   = (const float*)d_in[18];
    float* out = (float*)d_out;

    char* w = (char*)d_ws;
    const size_t MB = 1024 * 1024;
    char* qsh = w + 0 * MB;
    char* qsl = w + 1 * MB;
    char* qdh = w + 2 * MB;
    char* qdl = w + 3 * MB;
    char* csh = w + 4 * MB;
    char* csl = w + 6 * MB;
    char* cdh = w + 8 * MB;
    char* cdl = w + 10 * MB;
    float* cpart         = (float*)(w + 12 * MB);           // 32 MB [4][B][NC][DD]
    float* npart         = (float*)(w + 44 * MB);           // 32 MB [16][B][NV][DD]
    unsigned short* comp = (unsigned short*)(w + 76 * MB);  // 16 MB [B][256][NC]
    char* asgn           = w + 92 * MB;                     // 64 MB [B][128][NC][16]

    k_prep_pv<<<256, 256, 0, stream>>>(vars, cblk, qsh, qsl, qdh, qdl);
    k_compress<<<4096, 256, 0, stream>>>(cmat, asgn, comp);
    k_phaseA<<<1024, 256, 0, stream>>>(asgn, qsh, qsl, qdh, qdl, cpart);
    k_projC<<<1024, 256, 0, stream>>>(cpart, cb, vblk, csh, csl, cdh, cdl);
    k_phaseB<<<1024, 256, 0, stream>>>(comp, csh, csl, cdh, cdl, npart);
    k_gru<<<256, 512, 0, stream>>>(npart, vars, gv, vb, Wg, bg,
                                   Wz, Uz, bz, Wr, Ur, br_, Wh, Uh, bh, out);
}

// Round 11
// 164.286 us; speedup vs baseline: 1.1340x; 1.1340x over previous
//
#include <hip/hip_runtime.h>
#include <hip/hip_bf16.h>
#include <stdint.h>

#define NBATCH 4
#define NV 2048
#define NC 8192
#define DD 64

typedef __attribute__((ext_vector_type(8))) short s16x8;
typedef __attribute__((ext_vector_type(4))) float fx4;
typedef __attribute__((ext_vector_type(8))) unsigned short u16x8;
typedef __attribute__((ext_vector_type(4))) int i32x4;
typedef __attribute__((ext_vector_type(2))) unsigned int u32x2;

static __device__ __forceinline__ void gload_lds16(const void* g, void* l) {
    __builtin_amdgcn_global_load_lds(
        (const __attribute__((address_space(1))) unsigned int*)g,
        (__attribute__((address_space(3))) unsigned int*)l, 16, 0, 0);
}

// ---------------------------------------------------------------------------
// K0: s=(pos+neg)/2, d=(pos-neg)/2 of variables @ c_block[pn]^T, quantized to
// int16 (scale 2^12), split hi/lo i8, i8 MFMA B-frag layout.
// ---------------------------------------------------------------------------
__global__ __launch_bounds__(256) void k_prep_pv(
    const float* __restrict__ vars, const float* __restrict__ cblk,
    char* __restrict__ qsh, char* __restrict__ qsl,
    char* __restrict__ qdh, char* __restrict__ qdl)
{
    __shared__ float sv[32][64];
    __shared__ float scb[2][64][65];
    int blk = blockIdx.x;
    int b = blk >> 6, ch = blk & 63;
    int t = threadIdx.x;
    const float* vsrc = vars + ((size_t)b * NV + (size_t)ch * 32) * DD;
    for (int i = t; i < 32 * 64; i += 256) sv[i >> 6][i & 63] = vsrc[i];
    for (int i = t; i < 2 * 64 * 64; i += 256) {
        int pn = i >> 12, dout = (i >> 6) & 63, k = i & 63;
        scb[pn][k][dout] = cblk[i];
    }
    __syncthreads();
    int ks = t >> 6, dout = t & 63;
    unsigned int wsh[2] = {0, 0}, wsl[2] = {0, 0}, wdh[2] = {0, 0}, wdl[2] = {0, 0};
    #pragma unroll
    for (int c8 = 0; c8 < 8; ++c8) {
        int vloc = ks * 8 + c8;
        float ap = 0.f, an = 0.f;
        for (int k = 0; k < 64; ++k) {
            float vv = sv[vloc][k];
            ap += vv * scb[0][k][dout];
            an += vv * scb[1][k][dout];
        }
        float s = (ap + an) * 0.5f, dv = (ap - an) * 0.5f;
        int qs_ = (int)rintf(s * 4096.f);
        int qd_ = (int)rintf(dv * 4096.f);
        qs_ = min(max(qs_, -32511), 32511);
        qd_ = min(max(qd_, -32511), 32511);
        int sh = (qs_ + 128) >> 8, sl = qs_ - (sh << 8);
        int dh = (qd_ + 128) >> 8, dl = qd_ - (dh << 8);
        int w = c8 >> 2, sft = (c8 & 3) * 8;
        wsh[w] |= (unsigned int)(sh & 0xFF) << sft;
        wsl[w] |= (unsigned int)(sl & 0xFF) << sft;
        wdh[w] |= (unsigned int)(dh & 0xFF) << sft;
        wdl[w] |= (unsigned int)(dl & 0xFF) << sft;
    }
    int kc = ch >> 1;
    int lg = ((ch & 1) << 1) | (ks >> 1);
    size_t off = (((size_t)(b * 32 + kc) * 64 + dout) * 4 + lg) * 16 + (ks & 1) * 8;
    *(u32x2*)(qsh + off) = (u32x2){wsh[0], wsh[1]};
    *(u32x2*)(qsl + off) = (u32x2){wsl[0], wsl[1]};
    *(u32x2*)(qdh + off) = (u32x2){wdh[0], wdh[1]};
    *(u32x2*)(qdl + off) = (u32x2){wdl[0], wdl[1]};
}

// ---------------------------------------------------------------------------
// K-compress: pure HBM stream. cmat (256 MB f32) -> comp 2-bit codes
// [b][v8=0..255][crow] ushort (16 MB). 64 rows x 256 vars per block,
// LDS transpose, coalesced 1KB reads / 128B-segment writes.
// grid 4096 x 256: blk = b*1024 + rg*8 + tv.
// ---------------------------------------------------------------------------
__global__ __launch_bounds__(256) void k_compress(
    const float* __restrict__ cmat, unsigned short* __restrict__ comp)
{
    __shared__ char sb[64][260];
    int blk = blockIdx.x;
    int tv = blk & 7;
    int rg = (blk >> 3) & 127;
    int b = blk >> 10;
    int t = threadIdx.x;
    int wv = t >> 6, l = t & 63;
    int crow0 = rg * 64;
    const float* src = cmat + (size_t)b * NC * NV + (size_t)crow0 * NV + tv * 256;
    #pragma unroll 4
    for (int rr = 0; rr < 16; ++rr) {
        int r = wv * 16 + rr;
        fx4 x = *(const fx4*)(src + (size_t)r * NV + l * 4);
        unsigned int pk = ((unsigned int)((int)x[0] & 0xFF))
                        | (((unsigned int)((int)x[1] & 0xFF)) << 8)
                        | (((unsigned int)((int)x[2] & 0xFF)) << 16)
                        | (((unsigned int)((int)x[3] & 0xFF)) << 24);
        *(unsigned int*)&sb[r][l * 4] = pk;
    }
    __syncthreads();
    unsigned short* cbp = comp + ((size_t)b * 256 + tv * 32) * NC + crow0;
    #pragma unroll
    for (int it = 0; it < 8; ++it) {
        int idx = it * 256 + t;
        int v8l = idx >> 6, r = idx & 63;
        unsigned int lo = *(const unsigned int*)&sb[r][v8l * 8];
        unsigned int hi = *(const unsigned int*)&sb[r][v8l * 8 + 4];
        unsigned int c0 = 0;
        #pragma unroll
        for (int i = 0; i < 4; ++i) c0 |= ((lo >> (8 * i)) & 3u) << (2 * i);
        #pragma unroll
        for (int i = 0; i < 4; ++i) c0 |= ((hi >> (8 * i)) & 3u) << (8 + 2 * i);
        cbp[(size_t)v8l * NC + r] = (unsigned short)c0;
    }
}

// ---------------------------------------------------------------------------
// K1: i8 phase A consuming COMP (not cmat!). cpart[q][b][c][d] =
// (|A|@s + A@d) raw-scaled partial over K-quarter q. A-frags decoded from
// 2-bit codes (sign-extend). 128-row 4-wave blocks, B-planes gload_lds dbuf.
// grid 1024 x 256, 4 blocks/CU.
// ---------------------------------------------------------------------------
__global__ __launch_bounds__(256, 4) void k_phaseA(
    const unsigned short* __restrict__ comp,
    const char* __restrict__ qsh, const char* __restrict__ qsl,
    const char* __restrict__ qdh, const char* __restrict__ qdl,
    float* __restrict__ cpart)
{
    __shared__ char lds[2][16384];
    int blk = blockIdx.x;
    int combo = blk & 15;
    int rg = blk >> 4;
    int b = combo >> 2;
    int q = combo & 3;
    int t = threadIdx.x;
    int wv = t >> 6, l = t & 63, lr = l & 15, lg = l >> 4;
    int c0 = rg * 128 + wv * 32;
    const unsigned short* compb = comp + (size_t)b * 256 * NC;

    i32x4 ahi[2][4], alo[2][4];
    #pragma unroll
    for (int i = 0; i < 2; ++i)
        #pragma unroll
        for (int j = 0; j < 4; ++j) { ahi[i][j] = (i32x4){0,0,0,0}; alo[i][j] = (i32x4){0,0,0,0}; }

    {
        size_t gb = ((size_t)(b * 32 + q * 8)) * 4096 + (size_t)t * 16;
        char* lp = &lds[0][t * 16];
        gload_lds16(qsh + gb, lp);
        gload_lds16(qsl + gb, lp + 4096);
        gload_lds16(qdh + gb, lp + 8192);
        gload_lds16(qdl + gb, lp + 12288);
    }
    // prologue comp codes for chunk 0
    unsigned int u0[2], u1[2], u0n[2], u1n[2];
    #pragma unroll
    for (int rt = 0; rt < 2; ++rt) {
        int crow = c0 + rt * 16 + lr;
        size_t v8 = (size_t)(q * 64 + lg * 2);
        u0[rt] = compb[v8 * NC + crow];
        u1[rt] = compb[(v8 + 1) * NC + crow];
    }
    __syncthreads();

    int cur = 0;
    #pragma unroll 1
    for (int cc = 0; cc < 8; ++cc) {
        if (cc < 7) {
            size_t gb = ((size_t)(b * 32 + q * 8 + cc + 1)) * 4096 + (size_t)t * 16;
            char* lp = &lds[cur ^ 1][t * 16];
            gload_lds16(qsh + gb, lp);
            gload_lds16(qsl + gb, lp + 4096);
            gload_lds16(qdh + gb, lp + 8192);
            gload_lds16(qdl + gb, lp + 12288);
            #pragma unroll
            for (int rt = 0; rt < 2; ++rt) {
                int crow = c0 + rt * 16 + lr;
                size_t v8 = (size_t)(q * 64 + (cc + 1) * 8 + lg * 2);
                u0n[rt] = compb[v8 * NC + crow];
                u1n[rt] = compb[(v8 + 1) * NC + crow];
            }
        }
        // decode A: 16 sign bytes per rt from two ushorts (sign-extend 2-bit)
        i32x4 Asgn[2], Aabs[2];
        #pragma unroll
        for (int rt = 0; rt < 2; ++rt) {
            i32x4 sg;
            #pragma unroll
            for (int w = 0; w < 4; ++w) {
                unsigned int wg = 0;
                #pragma unroll
                for (int jj = 0; jj < 4; ++jj) {
                    int j = w * 4 + jj;
                    unsigned int u = (j < 8) ? u0[rt] : u1[rt];
                    int c = ((int)(u << (30 - 2 * (j & 7)))) >> 30;
                    wg |= ((unsigned int)c & 0xFFu) << (8 * jj);
                }
                sg[w] = (int)wg;
            }
            Asgn[rt] = sg;
            i32x4 ab;
            #pragma unroll
            for (int w = 0; w < 4; ++w) ab[w] = sg[w] & 0x01010101;
            Aabs[rt] = ab;
        }
        const char* bufp = lds[cur];
        #pragma unroll
        for (int n = 0; n < 4; ++n) {
            int boff = ((n * 16 + lr) * 4 + lg) * 16;
            i32x4 Bsh = *(const i32x4*)(bufp + boff);
            i32x4 Bsl = *(const i32x4*)(bufp + 4096 + boff);
            i32x4 Bdh = *(const i32x4*)(bufp + 8192 + boff);
            i32x4 Bdl = *(const i32x4*)(bufp + 12288 + boff);
            #pragma unroll
            for (int rt = 0; rt < 2; ++rt) {
                ahi[rt][n] = __builtin_amdgcn_mfma_i32_16x16x64_i8(Aabs[rt], Bsh, ahi[rt][n], 0, 0, 0);
                ahi[rt][n] = __builtin_amdgcn_mfma_i32_16x16x64_i8(Asgn[rt], Bdh, ahi[rt][n], 0, 0, 0);
                alo[rt][n] = __builtin_amdgcn_mfma_i32_16x16x64_i8(Aabs[rt], Bsl, alo[rt][n], 0, 0, 0);
                alo[rt][n] = __builtin_amdgcn_mfma_i32_16x16x64_i8(Asgn[rt], Bdl, alo[rt][n], 0, 0, 0);
            }
        }
        if (cc < 7) {
            #pragma unroll
            for (int rt = 0; rt < 2; ++rt) { u0[rt] = u0n[rt]; u1[rt] = u1n[rt]; }
        }
        __syncthreads();
        cur ^= 1;
    }
    float* dst = cpart + (((size_t)q * NBATCH + b) * NC + c0) * DD;
    #pragma unroll
    for (int rt = 0; rt < 2; ++rt)
        #pragma unroll
        for (int n = 0; n < 4; ++n)
            #pragma unroll
            for (int r = 0; r < 4; ++r) {
                float v = (float)(ahi[rt][n][r] * 256 + alo[rt][n][r]) * (1.0f / 4096.0f);
                dst[(size_t)(rt * 16 + lg * 4 + r) * DD + n * 16 + lr] = v;
            }
}

// ---------------------------------------------------------------------------
// K2: c = relu(sum_q cpart + cb); emit (c@v0^T +/- c@v1^T)/2 quantized int16
// (scale 2^9), split hi/lo i8, i8 B-frag layout.
// ---------------------------------------------------------------------------
__global__ __launch_bounds__(256) void k_projC(
    const float* __restrict__ cpart, const float* __restrict__ cb,
    const float* __restrict__ vblk,
    char* __restrict__ csh, char* __restrict__ csl,
    char* __restrict__ cdh, char* __restrict__ cdl)
{
    __shared__ float src[32][64];
    __shared__ float svb[2][64][65];
    int blk = blockIdx.x;
    int b = blk >> 8, kc32 = blk & 255;
    int t = threadIdx.x;
    const size_t qs = (size_t)NBATCH * NC * DD;
    const float* cs = cpart + ((size_t)b * NC + (size_t)kc32 * 32) * DD;
    for (int i = t; i < 2048; i += 256) {
        int k = i & 63;
        float v = cb[k];
        #pragma unroll
        for (int p = 0; p < 4; ++p) v += cs[i + p * qs];
        src[i >> 6][k] = fmaxf(v, 0.f);
    }
    for (int i = t; i < 8192; i += 256) {
        int pn = i >> 12, dout = (i >> 6) & 63, k = i & 63;
        svb[pn][k][dout] = vblk[i];
    }
    __syncthreads();
    int ks = t >> 6, dout = t & 63;
    float ap[8] = {0.f, 0.f, 0.f, 0.f, 0.f, 0.f, 0.f, 0.f};
    float an[8] = {0.f, 0.f, 0.f, 0.f, 0.f, 0.f, 0.f, 0.f};
    for (int k = 0; k < 64; ++k) {
        float w0 = svb[0][k][dout], w1 = svb[1][k][dout];
        #pragma unroll
        for (int c8 = 0; c8 < 8; ++c8) {
            float rc = src[ks * 8 + c8][k];
            ap[c8] += rc * w0;
            an[c8] += rc * w1;
        }
    }
    unsigned int wsh[2] = {0, 0}, wsl[2] = {0, 0}, wdh[2] = {0, 0}, wdl[2] = {0, 0};
    #pragma unroll
    for (int c8 = 0; c8 < 8; ++c8) {
        float s = (ap[c8] + an[c8]) * 0.5f, dv = (ap[c8] - an[c8]) * 0.5f;
        int q_s = (int)rintf(s * 512.f);
        int q_d = (int)rintf(dv * 512.f);
        q_s = min(max(q_s, -32511), 32511);
        q_d = min(max(q_d, -32511), 32511);
        int sh = (q_s + 128) >> 8, sl = q_s - (sh << 8);
        int dh = (q_d + 128) >> 8, dl = q_d - (dh << 8);
        int w = c8 >> 2, sft = (c8 & 3) * 8;
        wsh[w] |= (unsigned int)(sh & 0xFF) << sft;
        wsl[w] |= (unsigned int)(sl & 0xFF) << sft;
        wdh[w] |= (unsigned int)(dh & 0xFF) << sft;
        wdl[w] |= (unsigned int)(dl & 0xFF) << sft;
    }
    int kc = kc32 >> 1;
    int lgw = ((kc32 & 1) << 1) | (ks >> 1);
    size_t off = (((size_t)(b * 128 + kc) * 64 + dout) * 4 + lgw) * 16 + (ks & 1) * 8;
    *(u32x2*)(csh + off) = (u32x2){wsh[0], wsh[1]};
    *(u32x2*)(csl + off) = (u32x2){wsl[0], wsl[1]};
    *(u32x2*)(cdh + off) = (u32x2){wdh[0], wdh[1]};
    *(u32x2*)(cdl + off) = (u32x2){wdl[0], wdl[1]};
}

// ---------------------------------------------------------------------------
// K3: i8 phase B. npart[q][b][v][d] = (|A|@s + A@d)/512 over K-16th q,
// A decoded from comp codes. 128-row 4-wave blocks, gload_lds dbuf.
// grid 1024 x 256.
// ---------------------------------------------------------------------------
__global__ __launch_bounds__(256, 4) void k_phaseB(
    const unsigned short* __restrict__ comp,
    const char* __restrict__ csh, const char* __restrict__ csl,
    const char* __restrict__ cdh, const char* __restrict__ cdl,
    float* __restrict__ npart)
{
    __shared__ char lds[2][16384];
    int blk = blockIdx.x;
    int combo = blk & 63;
    int rg = blk >> 6;
    int b = combo >> 4;
    int q = combo & 15;
    int t = threadIdx.x;
    int wv = t >> 6, l = t & 63, lr = l & 15, lg = l >> 4;
    int v0 = rg * 128 + wv * 32;
    const unsigned short* compb = comp + (size_t)b * 256 * NC;
    int sh_ = 2 * (lr & 7);
    const unsigned short* cp0 = compb + (size_t)((v0 + lr) >> 3) * NC + q * 512 + lg * 16;
    const unsigned short* cp1 = compb + (size_t)((v0 + 16 + lr) >> 3) * NC + q * 512 + lg * 16;
    const size_t cbase = ((size_t)(b * 128 + q * 8)) * 4096;

    i32x4 ahi[2][4], alo[2][4];
    #pragma unroll
    for (int i = 0; i < 2; ++i)
        #pragma unroll
        for (int j = 0; j < 4; ++j) { ahi[i][j] = (i32x4){0,0,0,0}; alo[i][j] = (i32x4){0,0,0,0}; }

    {
        size_t gb = cbase + (size_t)t * 16;
        char* lp = &lds[0][t * 16];
        gload_lds16(csh + gb, lp);
        gload_lds16(csl + gb, lp + 4096);
        gload_lds16(cdh + gb, lp + 8192);
        gload_lds16(cdl + gb, lp + 12288);
    }
    __syncthreads();

    int cur = 0;
    #pragma unroll 1
    for (int cc = 0; cc < 8; ++cc) {
        u16x8 u00 = *(const u16x8*)(cp0 + cc * 64);
        u16x8 u01 = *(const u16x8*)(cp0 + cc * 64 + 8);
        u16x8 u10 = *(const u16x8*)(cp1 + cc * 64);
        u16x8 u11 = *(const u16x8*)(cp1 + cc * 64 + 8);
        if (cc < 7) {
            size_t gb = cbase + (size_t)(cc + 1) * 4096 + (size_t)t * 16;
            char* lp = &lds[cur ^ 1][t * 16];
            gload_lds16(csh + gb, lp);
            gload_lds16(csl + gb, lp + 4096);
            gload_lds16(cdh + gb, lp + 8192);
            gload_lds16(cdl + gb, lp + 12288);
        }
        i32x4 Asgn[2], Aabs[2];
        #pragma unroll
        for (int rt = 0; rt < 2; ++rt) {
            u16x8 ua = rt ? u10 : u00;
            u16x8 ub = rt ? u11 : u01;
            i32x4 sg;
            #pragma unroll
            for (int g = 0; g < 4; ++g) {
                unsigned int wg = 0;
                #pragma unroll
                for (int jj = 0; jj < 4; ++jj) {
                    int j = g * 4 + jj;
                    unsigned int code = ((unsigned int)(j < 8 ? ua[j & 7] : ub[j & 7]) >> sh_) & 3u;
                    unsigned int byt = (code == 3u) ? 0xFFu : code;
                    wg |= byt << (jj * 8);
                }
                sg[g] = (int)wg;
            }
            Asgn[rt] = sg;
            i32x4 ab;
            #pragma unroll
            for (int g = 0; g < 4; ++g) ab[g] = sg[g] & 0x01010101;
            Aabs[rt] = ab;
        }
        const char* bufp = lds[cur];
        #pragma unroll
        for (int n = 0; n < 4; ++n) {
            int boff = ((n * 16 + lr) * 4 + lg) * 16;
            i32x4 Bsh = *(const i32x4*)(bufp + boff);
            i32x4 Bsl = *(const i32x4*)(bufp + 4096 + boff);
            i32x4 Bdh = *(const i32x4*)(bufp + 8192 + boff);
            i32x4 Bdl = *(const i32x4*)(bufp + 12288 + boff);
            #pragma unroll
            for (int rt = 0; rt < 2; ++rt) {
                ahi[rt][n] = __builtin_amdgcn_mfma_i32_16x16x64_i8(Aabs[rt], Bsh, ahi[rt][n], 0, 0, 0);
                ahi[rt][n] = __builtin_amdgcn_mfma_i32_16x16x64_i8(Asgn[rt], Bdh, ahi[rt][n], 0, 0, 0);
                alo[rt][n] = __builtin_amdgcn_mfma_i32_16x16x64_i8(Aabs[rt], Bsl, alo[rt][n], 0, 0, 0);
                alo[rt][n] = __builtin_amdgcn_mfma_i32_16x16x64_i8(Asgn[rt], Bdl, alo[rt][n], 0, 0, 0);
            }
        }
        __syncthreads();
        cur ^= 1;
    }
    float* dst = npart + (((size_t)q * NBATCH + b) * NV + v0) * DD;
    #pragma unroll
    for (int rt = 0; rt < 2; ++rt)
        #pragma unroll
        for (int n = 0; n < 4; ++n)
            #pragma unroll
            for (int r = 0; r < 4; ++r) {
                float v = (float)(ahi[rt][n][r] * 256 + alo[rt][n][r]) * (1.0f / 512.0f);
                dst[(size_t)(rt * 16 + lg * 4 + r) * DD + n * 16 + lr] = v;
            }
}

// ---------------------------------------------------------------------------
// K4: v_emb=relu(sum_{q<16} npart+vb); av=tanh([g|v_emb]@Wg^T+bg); GRU -> out
// grid 256 x 512, 4 row-iterations per block.
// ---------------------------------------------------------------------------
__global__ __launch_bounds__(512) void k_gru(
    const float* __restrict__ npart, const float* __restrict__ vars,
    const float* __restrict__ gv, const float* __restrict__ vb,
    const float* __restrict__ Wg, const float* __restrict__ bg,
    const float* __restrict__ Wz, const float* __restrict__ Uz, const float* __restrict__ bz,
    const float* __restrict__ Wr, const float* __restrict__ Ur, const float* __restrict__ brr,
    const float* __restrict__ Wh, const float* __restrict__ Uh, const float* __restrict__ bh,
    float* __restrict__ out)
{
    __shared__ float sWg[72][65];
    __shared__ float sWz[64][65], sUz[64][65];
    __shared__ float sWr[64][65], sUr[64][65];
    __shared__ float sWh[64][65], sUh[64][65];
    __shared__ float scat[8][72];
    __shared__ float sprev[8][64];
    __shared__ float sav[8][64];
    __shared__ float srp[8][64];
    int t = threadIdx.x;
    for (int i = t * 4; i < 4608; i += 2048) {
        fx4 g4 = *(const fx4*)(Wg + i);
        int dout = i / 72, j = i - dout * 72;
        #pragma unroll
        for (int jj = 0; jj < 4; ++jj) sWg[j + jj][dout] = g4[jj];
    }
    for (int i = t * 4; i < 4096; i += 2048) {
        int dout = i >> 6, k = i & 63;
        fx4 a;
        a = *(const fx4*)(Wz + i);
        #pragma unroll
        for (int jj = 0; jj < 4; ++jj) sWz[k + jj][dout] = a[jj];
        a = *(const fx4*)(Uz + i);
        #pragma unroll
        for (int jj = 0; jj < 4; ++jj) sUz[k + jj][dout] = a[jj];
        a = *(const fx4*)(Wr + i);
        #pragma unroll
        for (int jj = 0; jj < 4; ++jj) sWr[k + jj][dout] = a[jj];
        a = *(const fx4*)(Ur + i);
        #pragma unroll
        for (int jj = 0; jj < 4; ++jj) sUr[k + jj][dout] = a[jj];
        a = *(const fx4*)(Wh + i);
        #pragma unroll
        for (int jj = 0; jj < 4; ++jj) sWh[k + jj][dout] = a[jj];
        a = *(const fx4*)(Uh + i);
        #pragma unroll
        for (int jj = 0; jj < 4; ++jj) sUh[k + jj][dout] = a[jj];
    }
    int rr = t >> 6, dout = t & 63;
    const size_t qs = (size_t)NBATCH * NV * DD;
    #pragma unroll 1
    for (int it = 0; it < 4; ++it) {
        size_t row = (size_t)blockIdx.x * 32 + it * 8 + rr;
        float prev = vars[row * 64 + dout];
        float ve = vb[dout];
        #pragma unroll
        for (int s = 0; s < 16; ++s) ve += npart[(size_t)s * qs + row * 64 + dout];
        ve = fmaxf(ve, 0.f);
        scat[rr][8 + dout] = ve;
        if (dout < 8) scat[rr][dout] = gv[row * 8 + dout];
        sprev[rr][dout] = prev;
        __syncthreads();
        float a = bg[dout];
        for (int j = 0; j < 72; ++j) a += scat[rr][j] * sWg[j][dout];
        float av = 1.f - 2.f / (__expf(2.f * a) + 1.f);
        sav[rr][dout] = av;
        __syncthreads();
        float zi = bz[dout], ri = brr[dout], hwa = 0.f;
        for (int k = 0; k < 64; ++k) {
            float ak = sav[rr][k], pk = sprev[rr][k];
            zi += ak * sWz[k][dout] + pk * sUz[k][dout];
            ri += ak * sWr[k][dout] + pk * sUr[k][dout];
            hwa += ak * sWh[k][dout];
        }
        float z = 1.f / (1.f + __expf(-zi));
        float rgate = 1.f / (1.f + __expf(-ri));
        srp[rr][dout] = rgate * prev;
        __syncthreads();
        float hin = bh[dout] + hwa;
        for (int k = 0; k < 64; ++k) hin += srp[rr][k] * sUh[k][dout];
        float ht = 1.f - 2.f / (__expf(2.f * hin) + 1.f);
        out[row * 64 + dout] = (1.f - z) * prev + z * ht;
        __syncthreads();
    }
}

// ---------------------------------------------------------------------------
extern "C" void kernel_launch(void* const* d_in, const int* in_sizes, int n_in,
                              void* d_out, int out_size, void* d_ws, size_t ws_size,
                              hipStream_t stream) {
    (void)in_sizes; (void)n_in; (void)out_size; (void)ws_size;
    const float* vars = (const float*)d_in[0];
    const float* gv   = (const float*)d_in[1];
    const float* cmat = (const float*)d_in[2];
    const float* cblk = (const float*)d_in[4];
    const float* vblk = (const float*)d_in[5];
    const float* vb   = (const float*)d_in[6];
    const float* cb   = (const float*)d_in[7];
    const float* Wg   = (const float*)d_in[8];
    const float* bg   = (const float*)d_in[9];
    const float* Wz   = (const float*)d_in[10];
    const float* Uz   = (const float*)d_in[11];
    const float* bz   = (const float*)d_in[12];
    const float* Wr   = (const float*)d_in[13];
    const float* Ur   = (const float*)d_in[14];
    const float* br_  = (const float*)d_in[15];
    const float* Wh   = (const float*)d_in[16];
    const float* Uh   = (const float*)d_in[17];
    const float* bh   = (const float*)d_in[18];
    float* out = (float*)d_out;

    char* w = (char*)d_ws;
    const size_t MB = 1024 * 1024;
    char* qsh = w + 0 * MB;
    char* qsl = w + 1 * MB;
    char* qdh = w + 2 * MB;
    char* qdl = w + 3 * MB;
    char* csh = w + 4 * MB;
    char* csl = w + 6 * MB;
    char* cdh = w + 8 * MB;
    char* cdl = w + 10 * MB;
    float* cpart         = (float*)(w + 12 * MB);           // 32 MB [4][B][NC][DD]
    float* npart         = (float*)(w + 44 * MB);           // 32 MB [16][B][NV][DD]
    unsigned short* comp = (unsigned short*)(w + 76 * MB);  // 16 MB [B][256][NC]

    k_prep_pv<<<256, 256, 0, stream>>>(vars, cblk, qsh, qsl, qdh, qdl);
    k_compress<<<4096, 256, 0, stream>>>(cmat, comp);
    k_phaseA<<<1024, 256, 0, stream>>>(comp, qsh, qsl, qdh, qdl, cpart);
    k_projC<<<1024, 256, 0, stream>>>(cpart, cb, vblk, csh, csl, cdh, cdl);
    k_phaseB<<<1024, 256, 0, stream>>>(comp, csh, csl, cdh, cdl, npart);
    k_gru<<<256, 512, 0, stream>>>(npart, vars, gv, vb, Wg, bg,
                                   Wz, Uz, bz, Wr, Ur, br_, Wh, Uh, bh, out);
}

// Round 12
// 152.007 us; speedup vs baseline: 1.2256x; 1.0808x over previous
//
#include <hip/hip_runtime.h>
#include <hip/hip_bf16.h>
#include <stdint.h>

#define NBATCH 4
#define NV 2048
#define NC 8192
#define DD 64

typedef __attribute__((ext_vector_type(8))) short s16x8;
typedef __attribute__((ext_vector_type(4))) float fx4;
typedef __attribute__((ext_vector_type(8))) unsigned short u16x8;
typedef __attribute__((ext_vector_type(4))) int i32x4;
typedef __attribute__((ext_vector_type(2))) unsigned int u32x2;

static __device__ __forceinline__ void gload_lds16(const void* g, void* l) {
    __builtin_amdgcn_global_load_lds(
        (const __attribute__((address_space(1))) unsigned int*)g,
        (__attribute__((address_space(3))) unsigned int*)l, 16, 0, 0);
}

// ---------------------------------------------------------------------------
// K-front: fused independent pre-work.
//  blocks [0,4096): compress — cmat (256 MB) -> comp 2-bit codes (16 MB)
//  blocks [4096,4352): prep — variables @ c_block -> int16(2^12) hi/lo i8
//                      planes in i8 MFMA B-frag layout
// ---------------------------------------------------------------------------
__global__ __launch_bounds__(256) void k_front(
    const float* __restrict__ cmat, unsigned short* __restrict__ comp,
    const float* __restrict__ vars, const float* __restrict__ cblk,
    char* __restrict__ qsh, char* __restrict__ qsl,
    char* __restrict__ qdh, char* __restrict__ qdl)
{
    __shared__ __align__(16) char pool[41472];
    int blk = blockIdx.x;
    int t = threadIdx.x;
    if (blk < 4096) {
        // ------- compress path -------
        char (*sb)[260] = (char(*)[260])pool;   // 64 x 260 = 16.6 KB
        int tv = blk & 7;
        int rg = (blk >> 3) & 127;
        int b = blk >> 10;
        int wv = t >> 6, l = t & 63;
        int crow0 = rg * 64;
        const float* src = cmat + (size_t)b * NC * NV + (size_t)crow0 * NV + tv * 256;
        #pragma unroll 4
        for (int rr = 0; rr < 16; ++rr) {
            int r = wv * 16 + rr;
            fx4 x = *(const fx4*)(src + (size_t)r * NV + l * 4);
            unsigned int pk = ((unsigned int)((int)x[0] & 0xFF))
                            | (((unsigned int)((int)x[1] & 0xFF)) << 8)
                            | (((unsigned int)((int)x[2] & 0xFF)) << 16)
                            | (((unsigned int)((int)x[3] & 0xFF)) << 24);
            *(unsigned int*)&sb[r][l * 4] = pk;
        }
        __syncthreads();
        unsigned short* cbp = comp + ((size_t)b * 256 + tv * 32) * NC + crow0;
        #pragma unroll
        for (int it = 0; it < 8; ++it) {
            int idx = it * 256 + t;
            int v8l = idx >> 6, r = idx & 63;
            unsigned int lo = *(const unsigned int*)&sb[r][v8l * 8];
            unsigned int hi = *(const unsigned int*)&sb[r][v8l * 8 + 4];
            unsigned int c0 = 0;
            #pragma unroll
            for (int i = 0; i < 4; ++i) c0 |= ((lo >> (8 * i)) & 3u) << (2 * i);
            #pragma unroll
            for (int i = 0; i < 4; ++i) c0 |= ((hi >> (8 * i)) & 3u) << (8 + 2 * i);
            cbp[(size_t)v8l * NC + r] = (unsigned short)c0;
        }
    } else {
        // ------- prep path -------
        float (*sv)[64] = (float(*)[64])pool;                    // 8 KB
        float (*scb)[65] = (float(*)[65])(pool + 8192);          // 33.3 KB (scb[pn*64+k][dout])
        int blk2 = blk - 4096;
        int b = blk2 >> 6, ch = blk2 & 63;
        const float* vsrc = vars + ((size_t)b * NV + (size_t)ch * 32) * DD;
        for (int i = t; i < 32 * 64; i += 256) sv[i >> 6][i & 63] = vsrc[i];
        for (int i = t; i < 2 * 64 * 64; i += 256) {
            int pn = i >> 12, dout = (i >> 6) & 63, k = i & 63;
            scb[pn * 64 + k][dout] = cblk[i];
        }
        __syncthreads();
        int ks = t >> 6, dout = t & 63;
        unsigned int wsh[2] = {0, 0}, wsl[2] = {0, 0}, wdh[2] = {0, 0}, wdl[2] = {0, 0};
        #pragma unroll
        for (int c8 = 0; c8 < 8; ++c8) {
            int vloc = ks * 8 + c8;
            float ap = 0.f, an = 0.f;
            for (int k = 0; k < 64; ++k) {
                float vv = sv[vloc][k];
                ap += vv * scb[k][dout];
                an += vv * scb[64 + k][dout];
            }
            float s = (ap + an) * 0.5f, dv = (ap - an) * 0.5f;
            int qs_ = (int)rintf(s * 4096.f);
            int qd_ = (int)rintf(dv * 4096.f);
            qs_ = min(max(qs_, -32511), 32511);
            qd_ = min(max(qd_, -32511), 32511);
            int sh = (qs_ + 128) >> 8, sl = qs_ - (sh << 8);
            int dh = (qd_ + 128) >> 8, dl = qd_ - (dh << 8);
            int w = c8 >> 2, sft = (c8 & 3) * 8;
            wsh[w] |= (unsigned int)(sh & 0xFF) << sft;
            wsl[w] |= (unsigned int)(sl & 0xFF) << sft;
            wdh[w] |= (unsigned int)(dh & 0xFF) << sft;
            wdl[w] |= (unsigned int)(dl & 0xFF) << sft;
        }
        int kc = ch >> 1;
        int lg = ((ch & 1) << 1) | (ks >> 1);
        size_t off = (((size_t)(b * 32 + kc) * 64 + dout) * 4 + lg) * 16 + (ks & 1) * 8;
        *(u32x2*)(qsh + off) = (u32x2){wsh[0], wsh[1]};
        *(u32x2*)(qsl + off) = (u32x2){wsl[0], wsl[1]};
        *(u32x2*)(qdh + off) = (u32x2){wdh[0], wdh[1]};
        *(u32x2*)(qdl + off) = (u32x2){wdl[0], wdl[1]};
    }
}

// ---------------------------------------------------------------------------
// K1 fused: phase A (full K=2048, comp-decoded A, i8 MFMA, exact i32 acc)
// + in-LDS projC epilogue: c = relu(acc/4096 + cb); cvars = (c@v0 +/- c@v1)/2
// quantized int16(2^9) hi/lo i8 planes, written in phase-B B-frag layout.
// Block: 64 clause rows, 4 waves x 16 rows, 32 dbuf chunks.
// grid 512 x 256 (blk = rg*4 + b  -> XCD shares b).
// ---------------------------------------------------------------------------
__global__ __launch_bounds__(256, 2) void k_phaseA(
    const unsigned short* __restrict__ comp,
    const char* __restrict__ qsh, const char* __restrict__ qsl,
    const char* __restrict__ qdh, const char* __restrict__ qdl,
    const float* __restrict__ cb, const float* __restrict__ vblk,
    char* __restrict__ csh, char* __restrict__ csl,
    char* __restrict__ cdh, char* __restrict__ cdl)
{
    __shared__ __align__(16) char pool[50176];
    int blk = blockIdx.x;
    int b = blk & 3;
    int rg = blk >> 2;                 // 0..127 clause chunk
    int t = threadIdx.x;
    int wv = t >> 6, l = t & 63, lr = l & 15, lg = l >> 4;
    int crow0 = rg * 64;
    int crow = crow0 + wv * 16 + lr;
    const unsigned short* compb = comp + (size_t)b * 256 * NC;

    i32x4 ahi[4], alo[4];
    #pragma unroll
    for (int n = 0; n < 4; ++n) { ahi[n] = (i32x4){0,0,0,0}; alo[n] = (i32x4){0,0,0,0}; }

    // prologue: stage chunk 0 + comp codes chunk 0
    {
        size_t gb = ((size_t)(b * 32)) * 4096 + (size_t)t * 16;
        char* lp = pool + t * 16;
        gload_lds16(qsh + gb, lp);
        gload_lds16(qsl + gb, lp + 4096);
        gload_lds16(qdh + gb, lp + 8192);
        gload_lds16(qdl + gb, lp + 12288);
    }
    unsigned int u0, u1, u0n, u1n;
    u0 = compb[(size_t)(lg * 2) * NC + crow];
    u1 = compb[(size_t)(lg * 2 + 1) * NC + crow];
    __syncthreads();

    int cur = 0;
    #pragma unroll 1
    for (int kc = 0; kc < 32; ++kc) {
        if (kc < 31) {
            size_t gb = ((size_t)(b * 32 + kc + 1)) * 4096 + (size_t)t * 16;
            char* lp = pool + (cur ^ 1) * 16384 + t * 16;
            gload_lds16(qsh + gb, lp);
            gload_lds16(qsl + gb, lp + 4096);
            gload_lds16(qdh + gb, lp + 8192);
            gload_lds16(qdl + gb, lp + 12288);
            size_t v8 = (size_t)((kc + 1) * 8 + lg * 2);
            u0n = compb[v8 * NC + crow];
            u1n = compb[(v8 + 1) * NC + crow];
        }
        // decode A: 16 sign bytes from two ushorts (2-bit sign-extend)
        i32x4 Asgn, Aabs;
        #pragma unroll
        for (int w = 0; w < 4; ++w) {
            unsigned int wg = 0;
            #pragma unroll
            for (int jj = 0; jj < 4; ++jj) {
                int j = w * 4 + jj;
                unsigned int u = (j < 8) ? u0 : u1;
                int c = ((int)(u << (30 - 2 * (j & 7)))) >> 30;
                wg |= ((unsigned int)c & 0xFFu) << (8 * jj);
            }
            Asgn[w] = (int)wg;
        }
        #pragma unroll
        for (int w = 0; w < 4; ++w) Aabs[w] = Asgn[w] & 0x01010101;
        const char* bufp = pool + cur * 16384;
        #pragma unroll
        for (int n = 0; n < 4; ++n) {
            int boff = ((n * 16 + lr) * 4 + lg) * 16;
            i32x4 Bsh = *(const i32x4*)(bufp + boff);
            i32x4 Bsl = *(const i32x4*)(bufp + 4096 + boff);
            i32x4 Bdh = *(const i32x4*)(bufp + 8192 + boff);
            i32x4 Bdl = *(const i32x4*)(bufp + 12288 + boff);
            ahi[n] = __builtin_amdgcn_mfma_i32_16x16x64_i8(Aabs, Bsh, ahi[n], 0, 0, 0);
            ahi[n] = __builtin_amdgcn_mfma_i32_16x16x64_i8(Asgn, Bdh, ahi[n], 0, 0, 0);
            alo[n] = __builtin_amdgcn_mfma_i32_16x16x64_i8(Aabs, Bsl, alo[n], 0, 0, 0);
            alo[n] = __builtin_amdgcn_mfma_i32_16x16x64_i8(Asgn, Bdl, alo[n], 0, 0, 0);
        }
        if (kc < 31) { u0 = u0n; u1 = u1n; }
        __syncthreads();
        cur ^= 1;
    }

    // ---- epilogue (LDS pool re-aliased): c[64][66] f32 + svb[2][64][65] ----
    int* sbC = (int*)pool;                                  // [64][66]
    float* sbCf = (float*)pool;
    float* svb = (float*)(pool + 64 * 66 * 4);              // [(pn*64+k)*65 + dout]
    // write exact combined acc (ahi*256+alo), each wave owns rows wv*16..+15
    #pragma unroll
    for (int n = 0; n < 4; ++n)
        #pragma unroll
        for (int r = 0; r < 4; ++r)
            sbC[(wv * 16 + lg * 4 + r) * 66 + n * 16 + lr] = ahi[n][r] * 256 + alo[n][r];
    // stage vblk transposed
    for (int i = t * 4; i < 8192; i += 1024) {
        fx4 g4 = *(const fx4*)(vblk + i);
        int pn = i >> 12, dout = (i >> 6) & 63, k0 = i & 63;
        #pragma unroll
        for (int jj = 0; jj < 4; ++jj) svb[(pn * 64 + k0 + jj) * 65 + dout] = g4[jj];
    }
    __syncthreads();
    // relu transform in place
    for (int idx = t; idx < 4096; idx += 256) {
        int row = idx >> 6, k = idx & 63;
        float f = (float)sbC[row * 66 + k] * (1.0f / 4096.0f) + cb[k];
        sbCf[row * 66 + k] = fmaxf(f, 0.f);
    }
    __syncthreads();
    // project 16 rows per thread (rows wv*16 + c8), dout = lane
    int dout = l;
    float ap[16], an[16];
    #pragma unroll
    for (int c8 = 0; c8 < 16; ++c8) { ap[c8] = 0.f; an[c8] = 0.f; }
    for (int k = 0; k < 64; ++k) {
        float w0 = svb[k * 65 + dout];
        float w1 = svb[(64 + k) * 65 + dout];
        #pragma unroll
        for (int c8 = 0; c8 < 16; ++c8) {
            float rc = sbCf[(wv * 16 + c8) * 66 + k];
            ap[c8] += rc * w0;
            an[c8] += rc * w1;
        }
    }
    unsigned int osh[4] = {0,0,0,0}, osl[4] = {0,0,0,0}, odh[4] = {0,0,0,0}, odl[4] = {0,0,0,0};
    #pragma unroll
    for (int c8 = 0; c8 < 16; ++c8) {
        float s = (ap[c8] + an[c8]) * 0.5f, dv = (ap[c8] - an[c8]) * 0.5f;
        int q_s = (int)rintf(s * 512.f);
        int q_d = (int)rintf(dv * 512.f);
        q_s = min(max(q_s, -32511), 32511);
        q_d = min(max(q_d, -32511), 32511);
        int sh = (q_s + 128) >> 8, sl = q_s - (sh << 8);
        int dh = (q_d + 128) >> 8, dl = q_d - (dh << 8);
        int w = c8 >> 2, sft = (c8 & 3) * 8;
        osh[w] |= (unsigned int)(sh & 0xFF) << sft;
        osl[w] |= (unsigned int)(sl & 0xFF) << sft;
        odh[w] |= (unsigned int)(dh & 0xFF) << sft;
        odl[w] |= (unsigned int)(dl & 0xFF) << sft;
    }
    size_t off = (((size_t)(b * 128 + rg) * 64 + dout) * 64) + wv * 16;
    *(i32x4*)(csh + off) = (i32x4){(int)osh[0], (int)osh[1], (int)osh[2], (int)osh[3]};
    *(i32x4*)(csl + off) = (i32x4){(int)osl[0], (int)osl[1], (int)osl[2], (int)osl[3]};
    *(i32x4*)(cdh + off) = (i32x4){(int)odh[0], (int)odh[1], (int)odh[2], (int)odh[3]};
    *(i32x4*)(cdl + off) = (i32x4){(int)odl[0], (int)odl[1], (int)odl[2], (int)odl[3]};
}

// ---------------------------------------------------------------------------
// K3: i8 phase B (r11 form). npart[q][b][v][d] = (|A|@s + A@d)/512 over
// K-16th q, A decoded from comp codes. 128-row 4-wave blocks, gload_lds dbuf.
// grid 1024 x 256.
// ---------------------------------------------------------------------------
__global__ __launch_bounds__(256, 4) void k_phaseB(
    const unsigned short* __restrict__ comp,
    const char* __restrict__ csh, const char* __restrict__ csl,
    const char* __restrict__ cdh, const char* __restrict__ cdl,
    float* __restrict__ npart)
{
    __shared__ char lds[2][16384];
    int blk = blockIdx.x;
    int combo = blk & 63;
    int rg = blk >> 6;
    int b = combo >> 4;
    int q = combo & 15;
    int t = threadIdx.x;
    int wv = t >> 6, l = t & 63, lr = l & 15, lg = l >> 4;
    int v0 = rg * 128 + wv * 32;
    const unsigned short* compb = comp + (size_t)b * 256 * NC;
    int sh_ = 2 * (lr & 7);
    const unsigned short* cp0 = compb + (size_t)((v0 + lr) >> 3) * NC + q * 512 + lg * 16;
    const unsigned short* cp1 = compb + (size_t)((v0 + 16 + lr) >> 3) * NC + q * 512 + lg * 16;
    const size_t cbase = ((size_t)(b * 128 + q * 8)) * 4096;

    i32x4 ahi[2][4], alo[2][4];
    #pragma unroll
    for (int i = 0; i < 2; ++i)
        #pragma unroll
        for (int j = 0; j < 4; ++j) { ahi[i][j] = (i32x4){0,0,0,0}; alo[i][j] = (i32x4){0,0,0,0}; }

    {
        size_t gb = cbase + (size_t)t * 16;
        char* lp = &lds[0][t * 16];
        gload_lds16(csh + gb, lp);
        gload_lds16(csl + gb, lp + 4096);
        gload_lds16(cdh + gb, lp + 8192);
        gload_lds16(cdl + gb, lp + 12288);
    }
    __syncthreads();

    int cur = 0;
    #pragma unroll 1
    for (int cc = 0; cc < 8; ++cc) {
        u16x8 u00 = *(const u16x8*)(cp0 + cc * 64);
        u16x8 u01 = *(const u16x8*)(cp0 + cc * 64 + 8);
        u16x8 u10 = *(const u16x8*)(cp1 + cc * 64);
        u16x8 u11 = *(const u16x8*)(cp1 + cc * 64 + 8);
        if (cc < 7) {
            size_t gb = cbase + (size_t)(cc + 1) * 4096 + (size_t)t * 16;
            char* lp = &lds[cur ^ 1][t * 16];
            gload_lds16(csh + gb, lp);
            gload_lds16(csl + gb, lp + 4096);
            gload_lds16(cdh + gb, lp + 8192);
            gload_lds16(cdl + gb, lp + 12288);
        }
        i32x4 Asgn[2], Aabs[2];
        #pragma unroll
        for (int rt = 0; rt < 2; ++rt) {
            u16x8 ua = rt ? u10 : u00;
            u16x8 ub = rt ? u11 : u01;
            i32x4 sg;
            #pragma unroll
            for (int g = 0; g < 4; ++g) {
                unsigned int wg = 0;
                #pragma unroll
                for (int jj = 0; jj < 4; ++jj) {
                    int j = g * 4 + jj;
                    unsigned int code = ((unsigned int)(j < 8 ? ua[j & 7] : ub[j & 7]) >> sh_) & 3u;
                    unsigned int byt = (code == 3u) ? 0xFFu : code;
                    wg |= byt << (jj * 8);
                }
                sg[g] = (int)wg;
            }
            Asgn[rt] = sg;
            i32x4 ab;
            #pragma unroll
            for (int g = 0; g < 4; ++g) ab[g] = sg[g] & 0x01010101;
            Aabs[rt] = ab;
        }
        const char* bufp = &lds[cur][0];
        #pragma unroll
        for (int n = 0; n < 4; ++n) {
            int boff = ((n * 16 + lr) * 4 + lg) * 16;
            i32x4 Bsh = *(const i32x4*)(bufp + boff);
            i32x4 Bsl = *(const i32x4*)(bufp + 4096 + boff);
            i32x4 Bdh = *(const i32x4*)(bufp + 8192 + boff);
            i32x4 Bdl = *(const i32x4*)(bufp + 12288 + boff);
            #pragma unroll
            for (int rt = 0; rt < 2; ++rt) {
                ahi[rt][n] = __builtin_amdgcn_mfma_i32_16x16x64_i8(Aabs[rt], Bsh, ahi[rt][n], 0, 0, 0);
                ahi[rt][n] = __builtin_amdgcn_mfma_i32_16x16x64_i8(Asgn[rt], Bdh, ahi[rt][n], 0, 0, 0);
                alo[rt][n] = __builtin_amdgcn_mfma_i32_16x16x64_i8(Aabs[rt], Bsl, alo[rt][n], 0, 0, 0);
                alo[rt][n] = __builtin_amdgcn_mfma_i32_16x16x64_i8(Asgn[rt], Bdl, alo[rt][n], 0, 0, 0);
            }
        }
        __syncthreads();
        cur ^= 1;
    }
    float* dst = npart + (((size_t)q * NBATCH + b) * NV + v0) * DD;
    #pragma unroll
    for (int rt = 0; rt < 2; ++rt)
        #pragma unroll
        for (int n = 0; n < 4; ++n)
            #pragma unroll
            for (int r = 0; r < 4; ++r) {
                float v = (float)(ahi[rt][n][r] * 256 + alo[rt][n][r]) * (1.0f / 512.0f);
                dst[(size_t)(rt * 16 + lg * 4 + r) * DD + n * 16 + lr] = v;
            }
}

// ---------------------------------------------------------------------------
// K4: v_emb=relu(sum_{q<16} npart+vb); av=tanh([g|v_emb]@Wg^T+bg); GRU -> out
// grid 256 x 512, 4 row-iterations per block.
// ---------------------------------------------------------------------------
__global__ __launch_bounds__(512) void k_gru(
    const float* __restrict__ npart, const float* __restrict__ vars,
    const float* __restrict__ gv, const float* __restrict__ vb,
    const float* __restrict__ Wg, const float* __restrict__ bg,
    const float* __restrict__ Wz, const float* __restrict__ Uz, const float* __restrict__ bz,
    const float* __restrict__ Wr, const float* __restrict__ Ur, const float* __restrict__ brr,
    const float* __restrict__ Wh, const float* __restrict__ Uh, const float* __restrict__ bh,
    float* __restrict__ out)
{
    __shared__ float sWg[72][65];
    __shared__ float sWz[64][65], sUz[64][65];
    __shared__ float sWr[64][65], sUr[64][65];
    __shared__ float sWh[64][65], sUh[64][65];
    __shared__ float scat[8][72];
    __shared__ float sprev[8][64];
    __shared__ float sav[8][64];
    __shared__ float srp[8][64];
    int t = threadIdx.x;
    for (int i = t * 4; i < 4608; i += 2048) {
        fx4 g4 = *(const fx4*)(Wg + i);
        int dout = i / 72, j = i - dout * 72;
        #pragma unroll
        for (int jj = 0; jj < 4; ++jj) sWg[j + jj][dout] = g4[jj];
    }
    for (int i = t * 4; i < 4096; i += 2048) {
        int dout = i >> 6, k = i & 63;
        fx4 a;
        a = *(const fx4*)(Wz + i);
        #pragma unroll
        for (int jj = 0; jj < 4; ++jj) sWz[k + jj][dout] = a[jj];
        a = *(const fx4*)(Uz + i);
        #pragma unroll
        for (int jj = 0; jj < 4; ++jj) sUz[k + jj][dout] = a[jj];
        a = *(const fx4*)(Wr + i);
        #pragma unroll
        for (int jj = 0; jj < 4; ++jj) sWr[k + jj][dout] = a[jj];
        a = *(const fx4*)(Ur + i);
        #pragma unroll
        for (int jj = 0; jj < 4; ++jj) sUr[k + jj][dout] = a[jj];
        a = *(const fx4*)(Wh + i);
        #pragma unroll
        for (int jj = 0; jj < 4; ++jj) sWh[k + jj][dout] = a[jj];
        a = *(const fx4*)(Uh + i);
        #pragma unroll
        for (int jj = 0; jj < 4; ++jj) sUh[k + jj][dout] = a[jj];
    }
    int rr = t >> 6, dout = t & 63;
    const size_t qs = (size_t)NBATCH * NV * DD;
    #pragma unroll 1
    for (int it = 0; it < 4; ++it) {
        size_t row = (size_t)blockIdx.x * 32 + it * 8 + rr;
        float prev = vars[row * 64 + dout];
        float ve = vb[dout];
        #pragma unroll
        for (int s = 0; s < 16; ++s) ve += npart[(size_t)s * qs + row * 64 + dout];
        ve = fmaxf(ve, 0.f);
        scat[rr][8 + dout] = ve;
        if (dout < 8) scat[rr][dout] = gv[row * 8 + dout];
        sprev[rr][dout] = prev;
        __syncthreads();
        float a = bg[dout];
        for (int j = 0; j < 72; ++j) a += scat[rr][j] * sWg[j][dout];
        float av = 1.f - 2.f / (__expf(2.f * a) + 1.f);
        sav[rr][dout] = av;
        __syncthreads();
        float zi = bz[dout], ri = brr[dout], hwa = 0.f;
        for (int k = 0; k < 64; ++k) {
            float ak = sav[rr][k], pk = sprev[rr][k];
            zi += ak * sWz[k][dout] + pk * sUz[k][dout];
            ri += ak * sWr[k][dout] + pk * sUr[k][dout];
            hwa += ak * sWh[k][dout];
        }
        float z = 1.f / (1.f + __expf(-zi));
        float rgate = 1.f / (1.f + __expf(-ri));
        srp[rr][dout] = rgate * prev;
        __syncthreads();
        float hin = bh[dout] + hwa;
        for (int k = 0; k < 64; ++k) hin += srp[rr][k] * sUh[k][dout];
        float ht = 1.f - 2.f / (__expf(2.f * hin) + 1.f);
        out[row * 64 + dout] = (1.f - z) * prev + z * ht;
        __syncthreads();
    }
}

// ---------------------------------------------------------------------------
extern "C" void kernel_launch(void* const* d_in, const int* in_sizes, int n_in,
                              void* d_out, int out_size, void* d_ws, size_t ws_size,
                              hipStream_t stream) {
    (void)in_sizes; (void)n_in; (void)out_size; (void)ws_size;
    const float* vars = (const float*)d_in[0];
    const float* gv   = (const float*)d_in[1];
    const float* cmat = (const float*)d_in[2];
    const float* cblk = (const float*)d_in[4];
    const float* vblk = (const float*)d_in[5];
    const float* vb   = (const float*)d_in[6];
    const float* cb   = (const float*)d_in[7];
    const float* Wg   = (const float*)d_in[8];
    const float* bg   = (const float*)d_in[9];
    const float* Wz   = (const float*)d_in[10];
    const float* Uz   = (const float*)d_in[11];
    const float* bz   = (const float*)d_in[12];
    const float* Wr   = (const float*)d_in[13];
    const float* Ur   = (const float*)d_in[14];
    const float* br_  = (const float*)d_in[15];
    const float* Wh   = (const float*)d_in[16];
    const float* Uh   = (const float*)d_in[17];
    const float* bh   = (const float*)d_in[18];
    float* out = (float*)d_out;

    char* w = (char*)d_ws;
    const size_t MB = 1024 * 1024;
    char* qsh = w + 0 * MB;
    char* qsl = w + 1 * MB;
    char* qdh = w + 2 * MB;
    char* qdl = w + 3 * MB;
    char* csh = w + 4 * MB;      // 2 MB each
    char* csl = w + 6 * MB;
    char* cdh = w + 8 * MB;
    char* cdl = w + 10 * MB;
    float* npart         = (float*)(w + 12 * MB);           // 32 MB [16][B][NV][DD]
    unsigned short* comp = (unsigned short*)(w + 44 * MB);  // 16 MB [B][256][NC]

    k_front<<<4352, 256, 0, stream>>>(cmat, comp, vars, cblk, qsh, qsl, qdh, qdl);
    k_phaseA<<<512, 256, 0, stream>>>(comp, qsh, qsl, qdh, qdl, cb, vblk,
                                      csh, csl, cdh, cdl);
    k_phaseB<<<1024, 256, 0, stream>>>(comp, csh, csl, cdh, cdl, npart);
    k_gru<<<256, 512, 0, stream>>>(npart, vars, gv, vb, Wg, bg,
                                   Wz, Uz, bz, Wr, Ur, br_, Wh, Uh, bh, out);
}